// Round 2
// baseline (837.824 us; speedup 1.0000x reference)
//
#include <hip/hip_runtime.h>

#define N_NODES 50000
#define N_EDGES 400000
#define DIM 128

// ---------------------------------------------------------------------------
// fc1: h = relu(x @ W1^T + b1)   (all fp32)
// Block: 256 threads, tile 64 rows x 128 cols, thread computes 8 rows x 4 cols.
// ---------------------------------------------------------------------------
__global__ __launch_bounds__(256, 2) void fc1_kernel(
    const float* __restrict__ x, const float* __restrict__ W,
    const float* __restrict__ b, float* __restrict__ h)
{
    __shared__ float As[64 * 36];    // A tile (64 rows x 32 k), padded stride 36
    __shared__ float Ws[32 * 128];   // W^T chunk: Ws[k][j]

    const int t    = threadIdx.x;
    const int row0 = blockIdx.x * 64;
    const int jg   = (t & 31) * 4;   // 4 output cols
    const int rg   = (t >> 5) * 8;   // 8 output rows (within tile)

    float acc[8][4];
    {
        float4 bb = *(const float4*)(b + jg);
#pragma unroll
        for (int r = 0; r < 8; ++r) {
            acc[r][0] = bb.x; acc[r][1] = bb.y; acc[r][2] = bb.z; acc[r][3] = bb.w;
        }
    }

    const int lr = t >> 2;            // staging row 0..63
    const int lk = (t & 3) * 8;       // staging k offset (8 floats per thread)
    int lrow = row0 + lr;
    if (lrow >= N_NODES) lrow = N_NODES - 1;   // clamp (stores are guarded)

    for (int kc = 0; kc < 4; ++kc) {
        // stage A tile
        {
            const float* ap = x + (size_t)lrow * DIM + kc * 32 + lk;
            float4 f0 = *(const float4*)ap;
            float4 f1 = *(const float4*)(ap + 4);
            float* dst = &As[lr * 36 + lk];
            *(float4*)dst       = f0;
            *(float4*)(dst + 4) = f1;
        }
        // stage W^T chunk: Ws[k][j] = W[j][kc*32+k]
#pragma unroll
        for (int p = 0; p < 2; ++p) {
            int c0  = p * 256 + t;       // 0..511
            int j   = c0 >> 2;           // 0..127
            int kof = (c0 & 3) * 8;      // 0,8,16,24
            const float* wp = W + (size_t)j * DIM + kc * 32 + kof;
            float4 w0 = *(const float4*)wp;
            float4 w1 = *(const float4*)(wp + 4);
            Ws[(kof + 0) * DIM + j] = w0.x;
            Ws[(kof + 1) * DIM + j] = w0.y;
            Ws[(kof + 2) * DIM + j] = w0.z;
            Ws[(kof + 3) * DIM + j] = w0.w;
            Ws[(kof + 4) * DIM + j] = w1.x;
            Ws[(kof + 5) * DIM + j] = w1.y;
            Ws[(kof + 6) * DIM + j] = w1.z;
            Ws[(kof + 7) * DIM + j] = w1.w;
        }
        __syncthreads();

#pragma unroll
        for (int k = 0; k < 32; k += 4) {
            float4 w0 = *(const float4*)(&Ws[(k + 0) * DIM + jg]);
            float4 w1 = *(const float4*)(&Ws[(k + 1) * DIM + jg]);
            float4 w2 = *(const float4*)(&Ws[(k + 2) * DIM + jg]);
            float4 w3 = *(const float4*)(&Ws[(k + 3) * DIM + jg]);
#pragma unroll
            for (int r = 0; r < 8; ++r) {
                float4 a = *(const float4*)(&As[(rg + r) * 36 + k]);
                acc[r][0] += a.x * w0.x; acc[r][0] += a.y * w1.x;
                acc[r][0] += a.z * w2.x; acc[r][0] += a.w * w3.x;
                acc[r][1] += a.x * w0.y; acc[r][1] += a.y * w1.y;
                acc[r][1] += a.z * w2.y; acc[r][1] += a.w * w3.y;
                acc[r][2] += a.x * w0.z; acc[r][2] += a.y * w1.z;
                acc[r][2] += a.z * w2.z; acc[r][2] += a.w * w3.z;
                acc[r][3] += a.x * w0.w; acc[r][3] += a.y * w1.w;
                acc[r][3] += a.z * w2.w; acc[r][3] += a.w * w3.w;
            }
        }
        __syncthreads();
    }

#pragma unroll
    for (int r = 0; r < 8; ++r) {
        int row = row0 + rg + r;
        if (row < N_NODES) {
            float4 o;
            o.x = fmaxf(acc[r][0], 0.f);
            o.y = fmaxf(acc[r][1], 0.f);
            o.z = fmaxf(acc[r][2], 0.f);
            o.w = fmaxf(acc[r][3], 0.f);
            *(float4*)(h + (size_t)row * DIM + jg) = o;
        }
    }
}

// ---------------------------------------------------------------------------
// scatter: agg[dst] += h[src] (fp32 atomics), deg[dst] += 1
// 32 threads per edge, each handles 4 floats (16B load).
// ---------------------------------------------------------------------------
__global__ __launch_bounds__(256) void scatter_kernel(
    const int* __restrict__ esrc, const int* __restrict__ edst,
    const float* __restrict__ h, float* __restrict__ agg, float* __restrict__ deg)
{
    int gid  = blockIdx.x * 256 + threadIdx.x;
    int e    = gid >> 5;
    if (e >= N_EDGES) return;
    int part = gid & 31;
    int src = esrc[e], dst = edst[e];
    if ((unsigned)src >= N_NODES || (unsigned)dst >= N_NODES) return; // safety guard
    float4 hv = *(const float4*)(h + (size_t)src * DIM + part * 4);
    if (part == 0) unsafeAtomicAdd(&deg[dst], 1.0f);
    float* ap = agg + (size_t)dst * DIM + part * 4;
    unsafeAtomicAdd(ap + 0, hv.x);
    unsafeAtomicAdd(ap + 1, hv.y);
    unsafeAtomicAdd(ap + 2, hv.z);
    unsafeAtomicAdd(ap + 3, hv.w);
}

// ---------------------------------------------------------------------------
// fc2: out = (agg/max(deg,1) + h) @ W2^T + b2, combine fused into A staging
// ---------------------------------------------------------------------------
__global__ __launch_bounds__(256, 2) void fc2_kernel(
    const float* __restrict__ agg, const float* __restrict__ deg,
    const float* __restrict__ h, const float* __restrict__ W,
    const float* __restrict__ b, float* __restrict__ out)
{
    __shared__ float As[64 * 36];
    __shared__ float Ws[32 * 128];

    const int t    = threadIdx.x;
    const int row0 = blockIdx.x * 64;
    const int jg   = (t & 31) * 4;
    const int rg   = (t >> 5) * 8;

    float acc[8][4];
    {
        float4 bb = *(const float4*)(b + jg);
#pragma unroll
        for (int r = 0; r < 8; ++r) {
            acc[r][0] = bb.x; acc[r][1] = bb.y; acc[r][2] = bb.z; acc[r][3] = bb.w;
        }
    }

    const int lr = t >> 2;
    const int lk = (t & 3) * 8;
    int lrow = row0 + lr;
    if (lrow >= N_NODES) lrow = N_NODES - 1;

    float dg = deg[lrow];
    if (dg < 1.f) dg = 1.f;
    const float inv = 1.f / dg;

    for (int kc = 0; kc < 4; ++kc) {
        // stage A tile: z = agg/deg + h  (fused combine)
        {
            const float* ap = agg + (size_t)lrow * DIM + kc * 32 + lk;
            const float* hp = h   + (size_t)lrow * DIM + kc * 32 + lk;
            float4 g0 = *(const float4*)ap;
            float4 g1 = *(const float4*)(ap + 4);
            float4 h0 = *(const float4*)hp;
            float4 h1 = *(const float4*)(hp + 4);
            float* dst = &As[lr * 36 + lk];
            float4 f0 = {g0.x * inv + h0.x, g0.y * inv + h0.y,
                         g0.z * inv + h0.z, g0.w * inv + h0.w};
            float4 f1 = {g1.x * inv + h1.x, g1.y * inv + h1.y,
                         g1.z * inv + h1.z, g1.w * inv + h1.w};
            *(float4*)dst       = f0;
            *(float4*)(dst + 4) = f1;
        }
#pragma unroll
        for (int p = 0; p < 2; ++p) {
            int c0  = p * 256 + t;
            int j   = c0 >> 2;
            int kof = (c0 & 3) * 8;
            const float* wp = W + (size_t)j * DIM + kc * 32 + kof;
            float4 w0 = *(const float4*)wp;
            float4 w1 = *(const float4*)(wp + 4);
            Ws[(kof + 0) * DIM + j] = w0.x;
            Ws[(kof + 1) * DIM + j] = w0.y;
            Ws[(kof + 2) * DIM + j] = w0.z;
            Ws[(kof + 3) * DIM + j] = w0.w;
            Ws[(kof + 4) * DIM + j] = w1.x;
            Ws[(kof + 5) * DIM + j] = w1.y;
            Ws[(kof + 6) * DIM + j] = w1.z;
            Ws[(kof + 7) * DIM + j] = w1.w;
        }
        __syncthreads();

#pragma unroll
        for (int k = 0; k < 32; k += 4) {
            float4 w0 = *(const float4*)(&Ws[(k + 0) * DIM + jg]);
            float4 w1 = *(const float4*)(&Ws[(k + 1) * DIM + jg]);
            float4 w2 = *(const float4*)(&Ws[(k + 2) * DIM + jg]);
            float4 w3 = *(const float4*)(&Ws[(k + 3) * DIM + jg]);
#pragma unroll
            for (int r = 0; r < 8; ++r) {
                float4 a = *(const float4*)(&As[(rg + r) * 36 + k]);
                acc[r][0] += a.x * w0.x; acc[r][0] += a.y * w1.x;
                acc[r][0] += a.z * w2.x; acc[r][0] += a.w * w3.x;
                acc[r][1] += a.x * w0.y; acc[r][1] += a.y * w1.y;
                acc[r][1] += a.z * w2.y; acc[r][1] += a.w * w3.y;
                acc[r][2] += a.x * w0.z; acc[r][2] += a.y * w1.z;
                acc[r][2] += a.z * w2.z; acc[r][2] += a.w * w3.z;
                acc[r][3] += a.x * w0.w; acc[r][3] += a.y * w1.w;
                acc[r][3] += a.z * w2.w; acc[r][3] += a.w * w3.w;
            }
        }
        __syncthreads();
    }

#pragma unroll
    for (int r = 0; r < 8; ++r) {
        int row = row0 + rg + r;
        if (row < N_NODES) {
            float4 o = {acc[r][0], acc[r][1], acc[r][2], acc[r][3]};
            *(float4*)(out + (size_t)row * DIM + jg) = o;
        }
    }
}

extern "C" void kernel_launch(void* const* d_in, const int* in_sizes, int n_in,
                              void* d_out, int out_size, void* d_ws, size_t ws_size,
                              hipStream_t stream)
{
    const float* x  = (const float*)d_in[0];
    const int*   ei = (const int*)d_in[1];   // [2][E] int32
    const float* W1 = (const float*)d_in[2];
    const float* b1 = (const float*)d_in[3];
    const float* W2 = (const float*)d_in[4];
    const float* b2 = (const float*)d_in[5];
    float* out = (float*)d_out;

    char* ws = (char*)d_ws;
    float* h   = (float*)ws;                                         // 25.6 MB
    float* agg = (float*)(ws + (size_t)N_NODES * DIM * 4);           // 25.6 MB
    float* deg = (float*)(ws + (size_t)N_NODES * DIM * 8);           // 200 KB

    // zero agg + deg (contiguous)
    hipMemsetAsync(agg, 0, (size_t)(N_NODES * DIM + N_NODES) * 4, stream);

    fc1_kernel<<<(N_NODES + 63) / 64, 256, 0, stream>>>(x, W1, b1, h);
    scatter_kernel<<<(N_EDGES * 32) / 256, 256, 0, stream>>>(
        ei, ei + N_EDGES, h, agg, deg);
    fc2_kernel<<<(N_NODES + 63) / 64, 256, 0, stream>>>(agg, deg, h, W2, b2, out);
}

// Round 3
// 333.656 us; speedup vs baseline: 2.5110x; 2.5110x over previous
//
#include <hip/hip_runtime.h>

#define N_NODES 50000
#define N_EDGES 400000
#define DIM 128

// ---------------------------------------------------------------------------
// fc1: h = relu(x @ W1^T + b1)   (all fp32)
// Block: 256 threads, tile 64 rows x 128 cols, thread computes 8 rows x 4 cols.
// ---------------------------------------------------------------------------
__global__ __launch_bounds__(256, 2) void fc1_kernel(
    const float* __restrict__ x, const float* __restrict__ W,
    const float* __restrict__ b, float* __restrict__ h)
{
    __shared__ float As[64 * 36];    // A tile (64 rows x 32 k), padded stride 36
    __shared__ float Ws[32 * 128];   // W^T chunk: Ws[k][j]

    const int t    = threadIdx.x;
    const int row0 = blockIdx.x * 64;
    const int jg   = (t & 31) * 4;   // 4 output cols
    const int rg   = (t >> 5) * 8;   // 8 output rows (within tile)

    float acc[8][4];
    {
        float4 bb = *(const float4*)(b + jg);
#pragma unroll
        for (int r = 0; r < 8; ++r) {
            acc[r][0] = bb.x; acc[r][1] = bb.y; acc[r][2] = bb.z; acc[r][3] = bb.w;
        }
    }

    const int lr = t >> 2;            // staging row 0..63
    const int lk = (t & 3) * 8;       // staging k offset (8 floats per thread)
    int lrow = row0 + lr;
    if (lrow >= N_NODES) lrow = N_NODES - 1;   // clamp (stores are guarded)

    for (int kc = 0; kc < 4; ++kc) {
        {
            const float* ap = x + (size_t)lrow * DIM + kc * 32 + lk;
            float4 f0 = *(const float4*)ap;
            float4 f1 = *(const float4*)(ap + 4);
            float* dst = &As[lr * 36 + lk];
            *(float4*)dst       = f0;
            *(float4*)(dst + 4) = f1;
        }
#pragma unroll
        for (int p = 0; p < 2; ++p) {
            int c0  = p * 256 + t;       // 0..511
            int j   = c0 >> 2;           // 0..127
            int kof = (c0 & 3) * 8;      // 0,8,16,24
            const float* wp = W + (size_t)j * DIM + kc * 32 + kof;
            float4 w0 = *(const float4*)wp;
            float4 w1 = *(const float4*)(wp + 4);
            Ws[(kof + 0) * DIM + j] = w0.x;
            Ws[(kof + 1) * DIM + j] = w0.y;
            Ws[(kof + 2) * DIM + j] = w0.z;
            Ws[(kof + 3) * DIM + j] = w0.w;
            Ws[(kof + 4) * DIM + j] = w1.x;
            Ws[(kof + 5) * DIM + j] = w1.y;
            Ws[(kof + 6) * DIM + j] = w1.z;
            Ws[(kof + 7) * DIM + j] = w1.w;
        }
        __syncthreads();

#pragma unroll
        for (int k = 0; k < 32; k += 4) {
            float4 w0 = *(const float4*)(&Ws[(k + 0) * DIM + jg]);
            float4 w1 = *(const float4*)(&Ws[(k + 1) * DIM + jg]);
            float4 w2 = *(const float4*)(&Ws[(k + 2) * DIM + jg]);
            float4 w3 = *(const float4*)(&Ws[(k + 3) * DIM + jg]);
#pragma unroll
            for (int r = 0; r < 8; ++r) {
                float4 a = *(const float4*)(&As[(rg + r) * 36 + k]);
                acc[r][0] += a.x * w0.x; acc[r][0] += a.y * w1.x;
                acc[r][0] += a.z * w2.x; acc[r][0] += a.w * w3.x;
                acc[r][1] += a.x * w0.y; acc[r][1] += a.y * w1.y;
                acc[r][1] += a.z * w2.y; acc[r][1] += a.w * w3.y;
                acc[r][2] += a.x * w0.z; acc[r][2] += a.y * w1.z;
                acc[r][2] += a.z * w2.z; acc[r][2] += a.w * w3.z;
                acc[r][3] += a.x * w0.w; acc[r][3] += a.y * w1.w;
                acc[r][3] += a.z * w2.w; acc[r][3] += a.w * w3.w;
            }
        }
        __syncthreads();
    }

#pragma unroll
    for (int r = 0; r < 8; ++r) {
        int row = row0 + rg + r;
        if (row < N_NODES) {
            float4 o;
            o.x = fmaxf(acc[r][0], 0.f);
            o.y = fmaxf(acc[r][1], 0.f);
            o.z = fmaxf(acc[r][2], 0.f);
            o.w = fmaxf(acc[r][3], 0.f);
            *(float4*)(h + (size_t)row * DIM + jg) = o;
        }
    }
}

// ---------------------------------------------------------------------------
// CSR build, step 1: histogram of destination nodes
// ---------------------------------------------------------------------------
__global__ __launch_bounds__(256) void count_kernel(
    const int* __restrict__ edst, int* __restrict__ counts)
{
    int e = blockIdx.x * 256 + threadIdx.x;
    if (e >= N_EDGES) return;
    int dst = edst[e];
    if ((unsigned)dst >= N_NODES) return;
    atomicAdd(&counts[dst], 1);
}

// ---------------------------------------------------------------------------
// CSR build, step 2: exclusive prefix sum -> row_ptr[N+1], cursor[N]
// Single block of 256 threads; each thread serially scans a 196-element chunk.
// ---------------------------------------------------------------------------
__global__ __launch_bounds__(256) void scan_kernel(
    const int* __restrict__ counts, int* __restrict__ row_ptr,
    int* __restrict__ cursor)
{
    __shared__ int sums[256];
    const int per = (N_NODES + 255) / 256;   // 196
    const int t = threadIdx.x;
    const int begin = t * per;
    const int end   = (begin + per < N_NODES) ? begin + per : N_NODES;

    int s = 0;
    for (int i = begin; i < end; ++i) s += counts[i];
    sums[t] = s;
    __syncthreads();

    if (t == 0) {
        int run = 0;
        for (int i = 0; i < 256; ++i) { int v = sums[i]; sums[i] = run; run += v; }
    }
    __syncthreads();

    int off = sums[t];
    for (int i = begin; i < end; ++i) {
        row_ptr[i] = off;
        cursor[i]  = off;
        off += counts[i];
    }
    if (t == 255) row_ptr[N_NODES] = off;
}

// ---------------------------------------------------------------------------
// CSR build, step 3: bucket edges by destination (store src index)
// ---------------------------------------------------------------------------
__global__ __launch_bounds__(256) void bucket_kernel(
    const int* __restrict__ esrc, const int* __restrict__ edst,
    int* __restrict__ cursor, int* __restrict__ esorted)
{
    int e = blockIdx.x * 256 + threadIdx.x;
    if (e >= N_EDGES) return;
    int src = esrc[e], dst = edst[e];
    if ((unsigned)src >= N_NODES || (unsigned)dst >= N_NODES) return;
    int pos = atomicAdd(&cursor[dst], 1);
    esorted[pos] = src;
}

// ---------------------------------------------------------------------------
// aggregate: z[n] = (sum_{src in in(n)} h[src]) / max(deg,1) + h[n]
// One 128-thread block per node; thread t owns dim t. Gathers are coalesced
// 512B row reads; index reads are wave-uniform (scalar path).
// ---------------------------------------------------------------------------
__global__ __launch_bounds__(128) void aggregate_kernel(
    const int* __restrict__ row_ptr, const int* __restrict__ esorted,
    const float* __restrict__ h, float* __restrict__ z)
{
    const int n = blockIdx.x;
    const int t = threadIdx.x;
    const int start = row_ptr[n];
    const int end   = row_ptr[n + 1];

    float acc = 0.f;
    int e = start;
    for (; e + 4 <= end; e += 4) {
        int s0 = esorted[e + 0];
        int s1 = esorted[e + 1];
        int s2 = esorted[e + 2];
        int s3 = esorted[e + 3];
        float v0 = h[(size_t)s0 * DIM + t];
        float v1 = h[(size_t)s1 * DIM + t];
        float v2 = h[(size_t)s2 * DIM + t];
        float v3 = h[(size_t)s3 * DIM + t];
        acc += v0; acc += v1; acc += v2; acc += v3;
    }
    for (; e < end; ++e) {
        acc += h[(size_t)esorted[e] * DIM + t];
    }

    int deg = end - start;
    float inv = (deg > 0) ? 1.f / (float)deg : 1.f;
    z[(size_t)n * DIM + t] = acc * inv + h[(size_t)n * DIM + t];
}

// ---------------------------------------------------------------------------
// fc2: out = z @ W2^T + b2  (plain GEMM, same tiling as fc1, no relu)
// ---------------------------------------------------------------------------
__global__ __launch_bounds__(256, 2) void fc2_kernel(
    const float* __restrict__ z, const float* __restrict__ W,
    const float* __restrict__ b, float* __restrict__ out)
{
    __shared__ float As[64 * 36];
    __shared__ float Ws[32 * 128];

    const int t    = threadIdx.x;
    const int row0 = blockIdx.x * 64;
    const int jg   = (t & 31) * 4;
    const int rg   = (t >> 5) * 8;

    float acc[8][4];
    {
        float4 bb = *(const float4*)(b + jg);
#pragma unroll
        for (int r = 0; r < 8; ++r) {
            acc[r][0] = bb.x; acc[r][1] = bb.y; acc[r][2] = bb.z; acc[r][3] = bb.w;
        }
    }

    const int lr = t >> 2;
    const int lk = (t & 3) * 8;
    int lrow = row0 + lr;
    if (lrow >= N_NODES) lrow = N_NODES - 1;

    for (int kc = 0; kc < 4; ++kc) {
        {
            const float* ap = z + (size_t)lrow * DIM + kc * 32 + lk;
            float4 f0 = *(const float4*)ap;
            float4 f1 = *(const float4*)(ap + 4);
            float* dst = &As[lr * 36 + lk];
            *(float4*)dst       = f0;
            *(float4*)(dst + 4) = f1;
        }
#pragma unroll
        for (int p = 0; p < 2; ++p) {
            int c0  = p * 256 + t;
            int j   = c0 >> 2;
            int kof = (c0 & 3) * 8;
            const float* wp = W + (size_t)j * DIM + kc * 32 + kof;
            float4 w0 = *(const float4*)wp;
            float4 w1 = *(const float4*)(wp + 4);
            Ws[(kof + 0) * DIM + j] = w0.x;
            Ws[(kof + 1) * DIM + j] = w0.y;
            Ws[(kof + 2) * DIM + j] = w0.z;
            Ws[(kof + 3) * DIM + j] = w0.w;
            Ws[(kof + 4) * DIM + j] = w1.x;
            Ws[(kof + 5) * DIM + j] = w1.y;
            Ws[(kof + 6) * DIM + j] = w1.z;
            Ws[(kof + 7) * DIM + j] = w1.w;
        }
        __syncthreads();

#pragma unroll
        for (int k = 0; k < 32; k += 4) {
            float4 w0 = *(const float4*)(&Ws[(k + 0) * DIM + jg]);
            float4 w1 = *(const float4*)(&Ws[(k + 1) * DIM + jg]);
            float4 w2 = *(const float4*)(&Ws[(k + 2) * DIM + jg]);
            float4 w3 = *(const float4*)(&Ws[(k + 3) * DIM + jg]);
#pragma unroll
            for (int r = 0; r < 8; ++r) {
                float4 a = *(const float4*)(&As[(rg + r) * 36 + k]);
                acc[r][0] += a.x * w0.x; acc[r][0] += a.y * w1.x;
                acc[r][0] += a.z * w2.x; acc[r][0] += a.w * w3.x;
                acc[r][1] += a.x * w0.y; acc[r][1] += a.y * w1.y;
                acc[r][1] += a.z * w2.y; acc[r][1] += a.w * w3.y;
                acc[r][2] += a.x * w0.z; acc[r][2] += a.y * w1.z;
                acc[r][2] += a.z * w2.z; acc[r][2] += a.w * w3.z;
                acc[r][3] += a.x * w0.w; acc[r][3] += a.y * w1.w;
                acc[r][3] += a.z * w2.w; acc[r][3] += a.w * w3.w;
            }
        }
        __syncthreads();
    }

#pragma unroll
    for (int r = 0; r < 8; ++r) {
        int row = row0 + rg + r;
        if (row < N_NODES) {
            float4 o = {acc[r][0], acc[r][1], acc[r][2], acc[r][3]};
            *(float4*)(out + (size_t)row * DIM + jg) = o;
        }
    }
}

extern "C" void kernel_launch(void* const* d_in, const int* in_sizes, int n_in,
                              void* d_out, int out_size, void* d_ws, size_t ws_size,
                              hipStream_t stream)
{
    const float* x  = (const float*)d_in[0];
    const int*   ei = (const int*)d_in[1];   // [2][E] int32
    const float* W1 = (const float*)d_in[2];
    const float* b1 = (const float*)d_in[3];
    const float* W2 = (const float*)d_in[4];
    const float* b2 = (const float*)d_in[5];
    float* out = (float*)d_out;

    const int* esrc = ei;
    const int* edst = ei + N_EDGES;

    char* ws = (char*)d_ws;
    size_t off = 0;
    float* h       = (float*)(ws + off); off += (size_t)N_NODES * DIM * 4;  // 25.6 MB
    float* z       = (float*)(ws + off); off += (size_t)N_NODES * DIM * 4;  // 25.6 MB
    int*   counts  = (int*)(ws + off);   off += (size_t)N_NODES * 4;
    int*   row_ptr = (int*)(ws + off);   off += (size_t)(N_NODES + 1) * 4;
    int*   cursor  = (int*)(ws + off);   off += (size_t)N_NODES * 4;
    int*   esorted = (int*)(ws + off);   off += (size_t)N_EDGES * 4;

    // zero the histogram
    hipMemsetAsync(counts, 0, (size_t)N_NODES * 4, stream);

    fc1_kernel<<<(N_NODES + 63) / 64, 256, 0, stream>>>(x, W1, b1, h);
    count_kernel<<<(N_EDGES + 255) / 256, 256, 0, stream>>>(edst, counts);
    scan_kernel<<<1, 256, 0, stream>>>(counts, row_ptr, cursor);
    bucket_kernel<<<(N_EDGES + 255) / 256, 256, 0, stream>>>(
        esrc, edst, cursor, esorted);
    aggregate_kernel<<<N_NODES, 128, 0, stream>>>(row_ptr, esorted, h, z);
    fc2_kernel<<<(N_NODES + 63) / 64, 256, 0, stream>>>(z, W2, b2, out);
}

// Round 4
// 222.582 us; speedup vs baseline: 3.7641x; 1.4990x over previous
//
#include <hip/hip_runtime.h>

#define N_NODES 50000
#define N_EDGES 400000
#define DIM 128
#define N_SCAN_BLK ((N_NODES + 255) / 256)   // 196

// ---------------------------------------------------------------------------
// fc1: h = relu(x @ W1^T + b1)   (all fp32)
// Block: 256 threads, tile 64 rows x 128 cols, thread computes 8 rows x 4 cols.
// ---------------------------------------------------------------------------
__global__ __launch_bounds__(256, 2) void fc1_kernel(
    const float* __restrict__ x, const float* __restrict__ W,
    const float* __restrict__ b, float* __restrict__ h)
{
    __shared__ float As[64 * 36];    // A tile (64 rows x 32 k), padded stride 36
    __shared__ float Ws[32 * 128];   // W^T chunk: Ws[k][j]

    const int t    = threadIdx.x;
    const int row0 = blockIdx.x * 64;
    const int jg   = (t & 31) * 4;   // 4 output cols
    const int rg   = (t >> 5) * 8;   // 8 output rows (within tile)

    float acc[8][4];
    {
        float4 bb = *(const float4*)(b + jg);
#pragma unroll
        for (int r = 0; r < 8; ++r) {
            acc[r][0] = bb.x; acc[r][1] = bb.y; acc[r][2] = bb.z; acc[r][3] = bb.w;
        }
    }

    const int lr = t >> 2;            // staging row 0..63
    const int lk = (t & 3) * 8;       // staging k offset (8 floats per thread)
    int lrow = row0 + lr;
    if (lrow >= N_NODES) lrow = N_NODES - 1;   // clamp (stores are guarded)

    for (int kc = 0; kc < 4; ++kc) {
        {
            const float* ap = x + (size_t)lrow * DIM + kc * 32 + lk;
            float4 f0 = *(const float4*)ap;
            float4 f1 = *(const float4*)(ap + 4);
            float* dst = &As[lr * 36 + lk];
            *(float4*)dst       = f0;
            *(float4*)(dst + 4) = f1;
        }
#pragma unroll
        for (int p = 0; p < 2; ++p) {
            int c0  = p * 256 + t;       // 0..511
            int j   = c0 >> 2;           // 0..127
            int kof = (c0 & 3) * 8;      // 0,8,16,24
            const float* wp = W + (size_t)j * DIM + kc * 32 + kof;
            float4 w0 = *(const float4*)wp;
            float4 w1 = *(const float4*)(wp + 4);
            Ws[(kof + 0) * DIM + j] = w0.x;
            Ws[(kof + 1) * DIM + j] = w0.y;
            Ws[(kof + 2) * DIM + j] = w0.z;
            Ws[(kof + 3) * DIM + j] = w0.w;
            Ws[(kof + 4) * DIM + j] = w1.x;
            Ws[(kof + 5) * DIM + j] = w1.y;
            Ws[(kof + 6) * DIM + j] = w1.z;
            Ws[(kof + 7) * DIM + j] = w1.w;
        }
        __syncthreads();

#pragma unroll
        for (int k = 0; k < 32; k += 4) {
            float4 w0 = *(const float4*)(&Ws[(k + 0) * DIM + jg]);
            float4 w1 = *(const float4*)(&Ws[(k + 1) * DIM + jg]);
            float4 w2 = *(const float4*)(&Ws[(k + 2) * DIM + jg]);
            float4 w3 = *(const float4*)(&Ws[(k + 3) * DIM + jg]);
#pragma unroll
            for (int r = 0; r < 8; ++r) {
                float4 a = *(const float4*)(&As[(rg + r) * 36 + k]);
                acc[r][0] += a.x * w0.x; acc[r][0] += a.y * w1.x;
                acc[r][0] += a.z * w2.x; acc[r][0] += a.w * w3.x;
                acc[r][1] += a.x * w0.y; acc[r][1] += a.y * w1.y;
                acc[r][1] += a.z * w2.y; acc[r][1] += a.w * w3.y;
                acc[r][2] += a.x * w0.z; acc[r][2] += a.y * w1.z;
                acc[r][2] += a.z * w2.z; acc[r][2] += a.w * w3.z;
                acc[r][3] += a.x * w0.w; acc[r][3] += a.y * w1.w;
                acc[r][3] += a.z * w2.w; acc[r][3] += a.w * w3.w;
            }
        }
        __syncthreads();
    }

#pragma unroll
    for (int r = 0; r < 8; ++r) {
        int row = row0 + rg + r;
        if (row < N_NODES) {
            float4 o;
            o.x = fmaxf(acc[r][0], 0.f);
            o.y = fmaxf(acc[r][1], 0.f);
            o.z = fmaxf(acc[r][2], 0.f);
            o.w = fmaxf(acc[r][3], 0.f);
            *(float4*)(h + (size_t)row * DIM + jg) = o;
        }
    }
}

// ---------------------------------------------------------------------------
// CSR build, step 1: histogram of destination nodes
// ---------------------------------------------------------------------------
__global__ __launch_bounds__(256) void count_kernel(
    const int* __restrict__ edst, int* __restrict__ counts)
{
    int e = blockIdx.x * 256 + threadIdx.x;
    if (e >= N_EDGES) return;
    int dst = edst[e];
    if ((unsigned)dst >= N_NODES) return;
    atomicAdd(&counts[dst], 1);
}

// ---------------------------------------------------------------------------
// CSR build, step 2a: per-block exclusive scan (256 elems/block) + block sums
// ---------------------------------------------------------------------------
__global__ __launch_bounds__(256) void scan_blocks_kernel(
    const int* __restrict__ counts, int* __restrict__ row_ptr,
    int* __restrict__ bsum)
{
    __shared__ int tmp[256];
    const int t = threadIdx.x;
    const int i = blockIdx.x * 256 + t;
    int v = (i < N_NODES) ? counts[i] : 0;
    tmp[t] = v;
    __syncthreads();
#pragma unroll
    for (int ofs = 1; ofs < 256; ofs <<= 1) {
        int add = (t >= ofs) ? tmp[t - ofs] : 0;
        __syncthreads();
        tmp[t] += add;
        __syncthreads();
    }
    if (i < N_NODES) row_ptr[i] = tmp[t] - v;       // local exclusive
    if (t == 255) bsum[blockIdx.x] = tmp[255];      // block total
}

// ---------------------------------------------------------------------------
// CSR build, step 2b: exclusive scan of the 196 block sums
// ---------------------------------------------------------------------------
__global__ __launch_bounds__(256) void scan_top_kernel(
    const int* __restrict__ bsum, int* __restrict__ boff)
{
    __shared__ int tmp[256];
    const int t = threadIdx.x;
    int v = (t < N_SCAN_BLK) ? bsum[t] : 0;
    tmp[t] = v;
    __syncthreads();
#pragma unroll
    for (int ofs = 1; ofs < 256; ofs <<= 1) {
        int add = (t >= ofs) ? tmp[t - ofs] : 0;
        __syncthreads();
        tmp[t] += add;
        __syncthreads();
    }
    if (t < N_SCAN_BLK) boff[t] = tmp[t] - v;       // exclusive
}

// ---------------------------------------------------------------------------
// CSR build, step 2c: add block offsets; init cursor; close row_ptr
// ---------------------------------------------------------------------------
__global__ __launch_bounds__(256) void scan_fixup_kernel(
    const int* __restrict__ boff, int* __restrict__ row_ptr,
    int* __restrict__ cursor)
{
    int i = blockIdx.x * 256 + threadIdx.x;
    if (i < N_NODES) {
        int r = row_ptr[i] + boff[blockIdx.x];
        row_ptr[i] = r;
        cursor[i]  = r;
    }
    if (i == 0) row_ptr[N_NODES] = N_EDGES;
}

// ---------------------------------------------------------------------------
// CSR build, step 3: bucket edges by destination (store src index)
// ---------------------------------------------------------------------------
__global__ __launch_bounds__(256) void bucket_kernel(
    const int* __restrict__ esrc, const int* __restrict__ edst,
    int* __restrict__ cursor, int* __restrict__ esorted)
{
    int e = blockIdx.x * 256 + threadIdx.x;
    if (e >= N_EDGES) return;
    int src = esrc[e], dst = edst[e];
    if ((unsigned)src >= N_NODES || (unsigned)dst >= N_NODES) return;
    int pos = atomicAdd(&cursor[dst], 1);
    esorted[pos] = src;
}

// ---------------------------------------------------------------------------
// aggregate: z[n] = (sum_{src in in(n)} h[src]) / max(deg,1) + h[n]
// One 128-thread block per node; thread t owns dim t.
// ---------------------------------------------------------------------------
__global__ __launch_bounds__(128) void aggregate_kernel(
    const int* __restrict__ row_ptr, const int* __restrict__ esorted,
    const float* __restrict__ h, float* __restrict__ z)
{
    const int n = blockIdx.x;
    const int t = threadIdx.x;
    const int start = row_ptr[n];
    const int end   = row_ptr[n + 1];

    float acc = 0.f;
    int e = start;
    for (; e + 4 <= end; e += 4) {
        int s0 = esorted[e + 0];
        int s1 = esorted[e + 1];
        int s2 = esorted[e + 2];
        int s3 = esorted[e + 3];
        float v0 = h[(size_t)s0 * DIM + t];
        float v1 = h[(size_t)s1 * DIM + t];
        float v2 = h[(size_t)s2 * DIM + t];
        float v3 = h[(size_t)s3 * DIM + t];
        acc += v0; acc += v1; acc += v2; acc += v3;
    }
    for (; e < end; ++e) {
        acc += h[(size_t)esorted[e] * DIM + t];
    }

    int deg = end - start;
    float inv = (deg > 0) ? 1.f / (float)deg : 1.f;
    z[(size_t)n * DIM + t] = acc * inv + h[(size_t)n * DIM + t];
}

// ---------------------------------------------------------------------------
// fc2: out = z @ W2^T + b2  (plain GEMM, same tiling as fc1, no relu)
// ---------------------------------------------------------------------------
__global__ __launch_bounds__(256, 2) void fc2_kernel(
    const float* __restrict__ z, const float* __restrict__ W,
    const float* __restrict__ b, float* __restrict__ out)
{
    __shared__ float As[64 * 36];
    __shared__ float Ws[32 * 128];

    const int t    = threadIdx.x;
    const int row0 = blockIdx.x * 64;
    const int jg   = (t & 31) * 4;
    const int rg   = (t >> 5) * 8;

    float acc[8][4];
    {
        float4 bb = *(const float4*)(b + jg);
#pragma unroll
        for (int r = 0; r < 8; ++r) {
            acc[r][0] = bb.x; acc[r][1] = bb.y; acc[r][2] = bb.z; acc[r][3] = bb.w;
        }
    }

    const int lr = t >> 2;
    const int lk = (t & 3) * 8;
    int lrow = row0 + lr;
    if (lrow >= N_NODES) lrow = N_NODES - 1;

    for (int kc = 0; kc < 4; ++kc) {
        {
            const float* ap = z + (size_t)lrow * DIM + kc * 32 + lk;
            float4 f0 = *(const float4*)ap;
            float4 f1 = *(const float4*)(ap + 4);
            float* dst = &As[lr * 36 + lk];
            *(float4*)dst       = f0;
            *(float4*)(dst + 4) = f1;
        }
#pragma unroll
        for (int p = 0; p < 2; ++p) {
            int c0  = p * 256 + t;
            int j   = c0 >> 2;
            int kof = (c0 & 3) * 8;
            const float* wp = W + (size_t)j * DIM + kc * 32 + kof;
            float4 w0 = *(const float4*)wp;
            float4 w1 = *(const float4*)(wp + 4);
            Ws[(kof + 0) * DIM + j] = w0.x;
            Ws[(kof + 1) * DIM + j] = w0.y;
            Ws[(kof + 2) * DIM + j] = w0.z;
            Ws[(kof + 3) * DIM + j] = w0.w;
            Ws[(kof + 4) * DIM + j] = w1.x;
            Ws[(kof + 5) * DIM + j] = w1.y;
            Ws[(kof + 6) * DIM + j] = w1.z;
            Ws[(kof + 7) * DIM + j] = w1.w;
        }
        __syncthreads();

#pragma unroll
        for (int k = 0; k < 32; k += 4) {
            float4 w0 = *(const float4*)(&Ws[(k + 0) * DIM + jg]);
            float4 w1 = *(const float4*)(&Ws[(k + 1) * DIM + jg]);
            float4 w2 = *(const float4*)(&Ws[(k + 2) * DIM + jg]);
            float4 w3 = *(const float4*)(&Ws[(k + 3) * DIM + jg]);
#pragma unroll
            for (int r = 0; r < 8; ++r) {
                float4 a = *(const float4*)(&As[(rg + r) * 36 + k]);
                acc[r][0] += a.x * w0.x; acc[r][0] += a.y * w1.x;
                acc[r][0] += a.z * w2.x; acc[r][0] += a.w * w3.x;
                acc[r][1] += a.x * w0.y; acc[r][1] += a.y * w1.y;
                acc[r][1] += a.z * w2.y; acc[r][1] += a.w * w3.y;
                acc[r][2] += a.x * w0.z; acc[r][2] += a.y * w1.z;
                acc[r][2] += a.z * w2.z; acc[r][2] += a.w * w3.z;
                acc[r][3] += a.x * w0.w; acc[r][3] += a.y * w1.w;
                acc[r][3] += a.z * w2.w; acc[r][3] += a.w * w3.w;
            }
        }
        __syncthreads();
    }

#pragma unroll
    for (int r = 0; r < 8; ++r) {
        int row = row0 + rg + r;
        if (row < N_NODES) {
            float4 o = {acc[r][0], acc[r][1], acc[r][2], acc[r][3]};
            *(float4*)(out + (size_t)row * DIM + jg) = o;
        }
    }
}

extern "C" void kernel_launch(void* const* d_in, const int* in_sizes, int n_in,
                              void* d_out, int out_size, void* d_ws, size_t ws_size,
                              hipStream_t stream)
{
    const float* x  = (const float*)d_in[0];
    const int*   ei = (const int*)d_in[1];   // [2][E] int32
    const float* W1 = (const float*)d_in[2];
    const float* b1 = (const float*)d_in[3];
    const float* W2 = (const float*)d_in[4];
    const float* b2 = (const float*)d_in[5];
    float* out = (float*)d_out;

    const int* esrc = ei;
    const int* edst = ei + N_EDGES;

    char* ws = (char*)d_ws;
    size_t off = 0;
    float* h       = (float*)(ws + off); off += (size_t)N_NODES * DIM * 4;  // 25.6 MB
    float* z       = (float*)(ws + off); off += (size_t)N_NODES * DIM * 4;  // 25.6 MB
    int*   counts  = (int*)(ws + off);   off += (size_t)N_NODES * 4;
    int*   row_ptr = (int*)(ws + off);   off += (size_t)(N_NODES + 1) * 4;
    int*   cursor  = (int*)(ws + off);   off += (size_t)N_NODES * 4;
    int*   esorted = (int*)(ws + off);   off += (size_t)N_EDGES * 4;
    int*   bsum    = (int*)(ws + off);   off += (size_t)N_SCAN_BLK * 4;
    int*   boff    = (int*)(ws + off);   off += (size_t)N_SCAN_BLK * 4;

    // zero the histogram
    hipMemsetAsync(counts, 0, (size_t)N_NODES * 4, stream);

    fc1_kernel<<<(N_NODES + 63) / 64, 256, 0, stream>>>(x, W1, b1, h);
    count_kernel<<<(N_EDGES + 255) / 256, 256, 0, stream>>>(edst, counts);
    scan_blocks_kernel<<<N_SCAN_BLK, 256, 0, stream>>>(counts, row_ptr, bsum);
    scan_top_kernel<<<1, 256, 0, stream>>>(bsum, boff);
    scan_fixup_kernel<<<N_SCAN_BLK, 256, 0, stream>>>(boff, row_ptr, cursor);
    bucket_kernel<<<(N_EDGES + 255) / 256, 256, 0, stream>>>(
        esrc, edst, cursor, esorted);
    aggregate_kernel<<<N_NODES, 128, 0, stream>>>(row_ptr, esorted, h, z);
    fc2_kernel<<<(N_NODES + 63) / 64, 256, 0, stream>>>(z, W2, b2, out);
}

// Round 5
// 181.931 us; speedup vs baseline: 4.6052x; 1.2234x over previous
//
#include <hip/hip_runtime.h>

#define N_NODES 50000
#define N_EDGES 400000
#define DIM 128
#define N_SCAN_BLK ((N_NODES + 255) / 256)   // 196

typedef unsigned short u16;
typedef unsigned int   u32;
typedef __bf16 v8bf  __attribute__((ext_vector_type(8)));
typedef float  f32x4 __attribute__((ext_vector_type(4)));
typedef u16    u16x8 __attribute__((ext_vector_type(8)));

union BF8 { u16x8 u; v8bf b; };

__device__ __forceinline__ float bf2f(u16 u) {
    union { u32 i; float f; } v; v.i = ((u32)u) << 16; return v.f;
}
__device__ __forceinline__ u16 f2bf(float f) {
    union { float f; u32 i; } v; v.f = f; u32 u = v.i;
    return (u16)((u + 0x7FFFu + ((u >> 16) & 1u)) >> 16);  // RNE
}

// ---------------------------------------------------------------------------
// cast W1/W2 fp32 -> bf16 (once per launch; 32K elems)
// ---------------------------------------------------------------------------
__global__ __launch_bounds__(256) void cast_w_kernel(
    const float* __restrict__ W1, const float* __restrict__ W2,
    u16* __restrict__ Wb1, u16* __restrict__ Wb2)
{
    int i = blockIdx.x * 256 + threadIdx.x;
    if (i < DIM * DIM) {
        Wb1[i] = f2bf(W1[i]);
        Wb2[i] = f2bf(W2[i]);
    }
}

// ---------------------------------------------------------------------------
// fc1: h = relu(x @ W1^T + b1)  via bf16 MFMA 16x16x32, fp32 accumulate.
// Block 256 (4 waves), tile 64 rows x 128 cols. Wave w: col-half w>>1,
// row-half w&1 (2 row-tiles x 4 col-tiles). B-frags held in registers.
// A: fragment layout A[m=lane&15][k=quad*8+j]; B[n=lane&15][k=quad*8+j]
// (= W row-major, contiguous); C/D: col=lane&15, row=quad*4+reg.
// ---------------------------------------------------------------------------
__global__ __launch_bounds__(256, 3) void fc1_mfma(
    const float* __restrict__ x, const u16* __restrict__ Wb,
    const float* __restrict__ b, u16* __restrict__ h)
{
    __shared__ u16 xs[64 * 136];   // stride 136 (=17*8): 2-way bank alias only
    const int t = threadIdx.x;
    const int wave = t >> 6, lane = t & 63, quad = lane >> 4, l15 = lane & 15;
    const int ch = wave >> 1, rh = wave & 1;
    const int row0 = blockIdx.x * 64;

    // B fragments for this wave's 4 col-tiles, all of K (hot in L1 after blk 0)
    BF8 barr[4][4];
#pragma unroll
    for (int ct = 0; ct < 4; ++ct)
#pragma unroll
        for (int ks = 0; ks < 4; ++ks)
            barr[ct][ks].u = *(const u16x8*)(
                Wb + (size_t)(ch * 64 + ct * 16 + l15) * DIM + ks * 32 + quad * 8);

    // stage x tile (fp32 -> bf16) into LDS
    {
        int srow = t >> 2, k0 = (t & 3) * 32;
        int grow = row0 + srow; if (grow >= N_NODES) grow = N_NODES - 1;
        const float* xp = x + (size_t)grow * DIM + k0;
#pragma unroll
        for (int j = 0; j < 4; ++j) {
            float4 f0 = *(const float4*)(xp + j * 8);
            float4 f1 = *(const float4*)(xp + j * 8 + 4);
            u16x8 p;
            p[0] = f2bf(f0.x); p[1] = f2bf(f0.y); p[2] = f2bf(f0.z); p[3] = f2bf(f0.w);
            p[4] = f2bf(f1.x); p[5] = f2bf(f1.y); p[6] = f2bf(f1.z); p[7] = f2bf(f1.w);
            *(u16x8*)&xs[srow * 136 + k0 + j * 8] = p;
        }
    }

    f32x4 acc[2][4];
#pragma unroll
    for (int ct = 0; ct < 4; ++ct) {
        float bv = b[ch * 64 + ct * 16 + l15];
        acc[0][ct] = (f32x4){bv, bv, bv, bv};
        acc[1][ct] = (f32x4){bv, bv, bv, bv};
    }
    __syncthreads();

#pragma unroll
    for (int ks = 0; ks < 4; ++ks) {
        BF8 a0, a1;
        a0.u = *(const u16x8*)&xs[(rh * 32 +  0 + l15) * 136 + ks * 32 + quad * 8];
        a1.u = *(const u16x8*)&xs[(rh * 32 + 16 + l15) * 136 + ks * 32 + quad * 8];
#pragma unroll
        for (int ct = 0; ct < 4; ++ct) {
            acc[0][ct] = __builtin_amdgcn_mfma_f32_16x16x32_bf16(
                a0.b, barr[ct][ks].b, acc[0][ct], 0, 0, 0);
            acc[1][ct] = __builtin_amdgcn_mfma_f32_16x16x32_bf16(
                a1.b, barr[ct][ks].b, acc[1][ct], 0, 0, 0);
        }
    }

#pragma unroll
    for (int rt = 0; rt < 2; ++rt)
#pragma unroll
        for (int i = 0; i < 4; ++i) {
            int row = row0 + rh * 32 + rt * 16 + quad * 4 + i;
            if (row < N_NODES) {
#pragma unroll
                for (int ct = 0; ct < 4; ++ct) {
                    int col = ch * 64 + ct * 16 + l15;
                    h[(size_t)row * DIM + col] = f2bf(fmaxf(acc[rt][ct][i], 0.f));
                }
            }
        }
}

// ---------------------------------------------------------------------------
// fc2: out = z @ W2^T + b2 (z bf16, out fp32), same MFMA structure
// ---------------------------------------------------------------------------
__global__ __launch_bounds__(256, 3) void fc2_mfma(
    const u16* __restrict__ z, const u16* __restrict__ Wb,
    const float* __restrict__ b, float* __restrict__ out)
{
    __shared__ u16 xs[64 * 136];
    const int t = threadIdx.x;
    const int wave = t >> 6, lane = t & 63, quad = lane >> 4, l15 = lane & 15;
    const int ch = wave >> 1, rh = wave & 1;
    const int row0 = blockIdx.x * 64;

    BF8 barr[4][4];
#pragma unroll
    for (int ct = 0; ct < 4; ++ct)
#pragma unroll
        for (int ks = 0; ks < 4; ++ks)
            barr[ct][ks].u = *(const u16x8*)(
                Wb + (size_t)(ch * 64 + ct * 16 + l15) * DIM + ks * 32 + quad * 8);

    // stage z tile (already bf16): plain 16B copies
    {
        int srow = t >> 1, k0 = (t & 1) * 64;
        int grow = row0 + srow; if (grow >= N_NODES) grow = N_NODES - 1;
        const u16* zp = z + (size_t)grow * DIM + k0;
#pragma unroll
        for (int j = 0; j < 8; ++j)
            *(u16x8*)&xs[srow * 136 + k0 + j * 8] = *(const u16x8*)(zp + j * 8);
    }

    f32x4 acc[2][4];
#pragma unroll
    for (int ct = 0; ct < 4; ++ct) {
        float bv = b[ch * 64 + ct * 16 + l15];
        acc[0][ct] = (f32x4){bv, bv, bv, bv};
        acc[1][ct] = (f32x4){bv, bv, bv, bv};
    }
    __syncthreads();

#pragma unroll
    for (int ks = 0; ks < 4; ++ks) {
        BF8 a0, a1;
        a0.u = *(const u16x8*)&xs[(rh * 32 +  0 + l15) * 136 + ks * 32 + quad * 8];
        a1.u = *(const u16x8*)&xs[(rh * 32 + 16 + l15) * 136 + ks * 32 + quad * 8];
#pragma unroll
        for (int ct = 0; ct < 4; ++ct) {
            acc[0][ct] = __builtin_amdgcn_mfma_f32_16x16x32_bf16(
                a0.b, barr[ct][ks].b, acc[0][ct], 0, 0, 0);
            acc[1][ct] = __builtin_amdgcn_mfma_f32_16x16x32_bf16(
                a1.b, barr[ct][ks].b, acc[1][ct], 0, 0, 0);
        }
    }

#pragma unroll
    for (int rt = 0; rt < 2; ++rt)
#pragma unroll
        for (int i = 0; i < 4; ++i) {
            int row = row0 + rh * 32 + rt * 16 + quad * 4 + i;
            if (row < N_NODES) {
#pragma unroll
                for (int ct = 0; ct < 4; ++ct) {
                    int col = ch * 64 + ct * 16 + l15;
                    out[(size_t)row * DIM + col] = acc[rt][ct][i];
                }
            }
        }
}

// ---------------------------------------------------------------------------
// CSR build
// ---------------------------------------------------------------------------
__global__ __launch_bounds__(256) void count_kernel(
    const int* __restrict__ edst, int* __restrict__ counts)
{
    int e = blockIdx.x * 256 + threadIdx.x;
    if (e >= N_EDGES) return;
    int dst = edst[e];
    if ((unsigned)dst >= N_NODES) return;
    atomicAdd(&counts[dst], 1);
}

__global__ __launch_bounds__(256) void scan_blocks_kernel(
    const int* __restrict__ counts, int* __restrict__ row_ptr,
    int* __restrict__ bsum)
{
    __shared__ int tmp[256];
    const int t = threadIdx.x;
    const int i = blockIdx.x * 256 + t;
    int v = (i < N_NODES) ? counts[i] : 0;
    tmp[t] = v;
    __syncthreads();
#pragma unroll
    for (int ofs = 1; ofs < 256; ofs <<= 1) {
        int add = (t >= ofs) ? tmp[t - ofs] : 0;
        __syncthreads();
        tmp[t] += add;
        __syncthreads();
    }
    if (i < N_NODES) row_ptr[i] = tmp[t] - v;
    if (t == 255) bsum[blockIdx.x] = tmp[255];
}

__global__ __launch_bounds__(256) void scan_top_kernel(
    const int* __restrict__ bsum, int* __restrict__ boff)
{
    __shared__ int tmp[256];
    const int t = threadIdx.x;
    int v = (t < N_SCAN_BLK) ? bsum[t] : 0;
    tmp[t] = v;
    __syncthreads();
#pragma unroll
    for (int ofs = 1; ofs < 256; ofs <<= 1) {
        int add = (t >= ofs) ? tmp[t - ofs] : 0;
        __syncthreads();
        tmp[t] += add;
        __syncthreads();
    }
    if (t < N_SCAN_BLK) boff[t] = tmp[t] - v;
}

__global__ __launch_bounds__(256) void scan_fixup_kernel(
    const int* __restrict__ boff, int* __restrict__ row_ptr,
    int* __restrict__ cursor)
{
    int i = blockIdx.x * 256 + threadIdx.x;
    if (i < N_NODES) {
        int r = row_ptr[i] + boff[blockIdx.x];
        row_ptr[i] = r;
        cursor[i]  = r;
    }
    if (i == 0) row_ptr[N_NODES] = N_EDGES;
}

__global__ __launch_bounds__(256) void bucket_kernel(
    const int* __restrict__ esrc, const int* __restrict__ edst,
    int* __restrict__ cursor, int* __restrict__ esorted)
{
    int e = blockIdx.x * 256 + threadIdx.x;
    if (e >= N_EDGES) return;
    int src = esrc[e], dst = edst[e];
    if ((unsigned)src >= N_NODES || (unsigned)dst >= N_NODES) return;
    int pos = atomicAdd(&cursor[dst], 1);
    esorted[pos] = src;
}

// ---------------------------------------------------------------------------
// aggregate: z[n] = mean(h[src in in(n)]) + h[n]   (h,z bf16; fp32 accumulate)
// One wave per node; lane t owns dims 2t,2t+1 (u32 = 2xbf16, 256B/row/wave).
// ---------------------------------------------------------------------------
__global__ __launch_bounds__(64) void aggregate_kernel(
    const int* __restrict__ row_ptr, const int* __restrict__ esorted,
    const u16* __restrict__ h, u16* __restrict__ z)
{
    const int n = blockIdx.x;
    const int t = threadIdx.x;
    const int start = row_ptr[n];
    const int end   = row_ptr[n + 1];

    float a0 = 0.f, a1 = 0.f;
    int e = start;
    for (; e + 4 <= end; e += 4) {
        int s0 = esorted[e + 0];
        int s1 = esorted[e + 1];
        int s2 = esorted[e + 2];
        int s3 = esorted[e + 3];
        u32 v0 = *(const u32*)(h + (size_t)s0 * DIM + t * 2);
        u32 v1 = *(const u32*)(h + (size_t)s1 * DIM + t * 2);
        u32 v2 = *(const u32*)(h + (size_t)s2 * DIM + t * 2);
        u32 v3 = *(const u32*)(h + (size_t)s3 * DIM + t * 2);
        a0 += bf2f((u16)v0); a1 += bf2f((u16)(v0 >> 16));
        a0 += bf2f((u16)v1); a1 += bf2f((u16)(v1 >> 16));
        a0 += bf2f((u16)v2); a1 += bf2f((u16)(v2 >> 16));
        a0 += bf2f((u16)v3); a1 += bf2f((u16)(v3 >> 16));
    }
    for (; e < end; ++e) {
        u32 v = *(const u32*)(h + (size_t)esorted[e] * DIM + t * 2);
        a0 += bf2f((u16)v); a1 += bf2f((u16)(v >> 16));
    }

    int deg = end - start;
    float inv = (deg > 0) ? 1.f / (float)deg : 1.f;
    u32 r = *(const u32*)(h + (size_t)n * DIM + t * 2);
    float z0 = a0 * inv + bf2f((u16)r);
    float z1 = a1 * inv + bf2f((u16)(r >> 16));
    u32 p = (u32)f2bf(z0) | ((u32)f2bf(z1) << 16);
    *(u32*)(z + (size_t)n * DIM + t * 2) = p;
}

extern "C" void kernel_launch(void* const* d_in, const int* in_sizes, int n_in,
                              void* d_out, int out_size, void* d_ws, size_t ws_size,
                              hipStream_t stream)
{
    const float* x  = (const float*)d_in[0];
    const int*   ei = (const int*)d_in[1];   // [2][E] int32
    const float* W1 = (const float*)d_in[2];
    const float* b1 = (const float*)d_in[3];
    const float* W2 = (const float*)d_in[4];
    const float* b2 = (const float*)d_in[5];
    float* out = (float*)d_out;

    const int* esrc = ei;
    const int* edst = ei + N_EDGES;

    char* ws = (char*)d_ws;
    size_t off = 0;
    u16* h        = (u16*)(ws + off); off += (size_t)N_NODES * DIM * 2;   // 12.8 MB
    u16* z        = (u16*)(ws + off); off += (size_t)N_NODES * DIM * 2;   // 12.8 MB
    u16* Wb1      = (u16*)(ws + off); off += (size_t)DIM * DIM * 2;       // 32 KB
    u16* Wb2      = (u16*)(ws + off); off += (size_t)DIM * DIM * 2;       // 32 KB
    int* counts   = (int*)(ws + off); off += (size_t)N_NODES * 4;
    int* row_ptr  = (int*)(ws + off); off += (size_t)(N_NODES + 1) * 4;
    int* cursor   = (int*)(ws + off); off += (size_t)N_NODES * 4;
    int* esorted  = (int*)(ws + off); off += (size_t)N_EDGES * 4;
    int* bsum     = (int*)(ws + off); off += (size_t)N_SCAN_BLK * 4;
    int* boff     = (int*)(ws + off); off += (size_t)N_SCAN_BLK * 4;

    hipMemsetAsync(counts, 0, (size_t)N_NODES * 4, stream);
    cast_w_kernel<<<(DIM * DIM + 255) / 256, 256, 0, stream>>>(W1, W2, Wb1, Wb2);

    fc1_mfma<<<(N_NODES + 63) / 64, 256, 0, stream>>>(x, Wb1, b1, h);
    count_kernel<<<(N_EDGES + 255) / 256, 256, 0, stream>>>(edst, counts);
    scan_blocks_kernel<<<N_SCAN_BLK, 256, 0, stream>>>(counts, row_ptr, bsum);
    scan_top_kernel<<<1, 256, 0, stream>>>(bsum, boff);
    scan_fixup_kernel<<<N_SCAN_BLK, 256, 0, stream>>>(boff, row_ptr, cursor);
    bucket_kernel<<<(N_EDGES + 255) / 256, 256, 0, stream>>>(
        esrc, edst, cursor, esorted);
    aggregate_kernel<<<N_NODES, 64, 0, stream>>>(row_ptr, esorted, h, z);
    fc2_mfma<<<(N_NODES + 63) / 64, 256, 0, stream>>>(z, Wb2, b2, out);
}